// Round 9
// baseline (103.867 us; speedup 1.0000x reference)
//
#include <hip/hip_runtime.h>
#include <hip/hip_bf16.h>

#define HM_W 512
#define HM_H 512
#define PW   508   // 512 - 5 + 1
#define NBATCH 128

__device__ __forceinline__ void load_row8(const float* __restrict__ hm, int y, int c0, float v[8]) {
    const float4* rp = reinterpret_cast<const float4*>(hm + y * HM_W + c0);
    float4 a = rp[0];
    float4 b = rp[1];
    v[0]=a.x; v[1]=a.y; v[2]=a.z; v[3]=a.w;
    v[4]=b.x; v[5]=b.y; v[6]=b.z; v[7]=b.w;
}

// Per-lane 5-wide window sums from per-lane colsums s[0..7] (cols lane*8..lane*8+7),
// cross-lane tail via shfl, then wave-wide argmax (tie-break: lowest column).
// Whole wave must be active. All lanes end with the result.
__device__ __forceinline__ void row_best_shfl(const float s[8], int lane, float& bv, int& bc) {
    float cb[12];
#pragma unroll
    for (int j = 0; j < 8; ++j) cb[j] = s[j];
#pragma unroll
    for (int j = 0; j < 4; ++j) cb[8 + j] = __shfl_down(s[j], 1);
    bv = -__builtin_inff();
    bc = 0x7fffffff;
    int c0 = lane * 8;
#pragma unroll
    for (int j = 0; j < 8; ++j) {
        int c = c0 + j;
        float w = cb[j] + cb[j + 1] + cb[j + 2] + cb[j + 3] + cb[j + 4];
        if (c < PW && w > bv) { bv = w; bc = c; }   // ascending c keeps lowest col on tie
    }
#pragma unroll
    for (int m = 1; m < 64; m <<= 1) {
        float ov = __shfl_xor(bv, m);
        int   oc = __shfl_xor(bc, m);
        if (ov > bv || (ov == bv && oc < bc)) { bv = ov; bc = oc; }
    }
}

// Fused kernel. Blocks 0..1023: phase-1 role (batch = blk>>3, strip = blk&7);
// each block covers 64 rows (4 waves x 16-row rolling window, r2-exact math),
// then publishes with __syncthreads + agent-scope RELEASE atomicAdd (drains
// stores, writes back XCD L2 to the coherent point). Blocks 1024..1151:
// phase-2 role for batch blk-1024; t0 spins on cnt[b]==8 with agent-scope
// ACQUIRE (invalidates local L2), then the r6 one-barrier-per-iteration
// peak-extraction with 4-wave repair (rows wave+4p, p<3).
// Deadlock-free: phase-1 never waits; capacity >= 4 blocks/CU so phase-1's
// 1024 blocks can always run even if all 128 phase-2 blocks sit spinning.
__global__ void __launch_bounds__(256) fused_kernel(const float* __restrict__ hm_all,
                              float* __restrict__ rowv_ws, int* __restrict__ rowc_ws,
                              int* __restrict__ cnt, int* __restrict__ out) {
    int t = threadIdx.x;
    int wave = t >> 6, lane = t & 63;
    int c0 = lane * 8;

    __shared__ float rowv[512];
    __shared__ int   rowc[512];
    __shared__ float updv[2][9];
    __shared__ int   updc[2][9];
    __shared__ int   upd_y0[2];
    __shared__ int   upd_n[2];

    if (blockIdx.x < 1024) {
        // ---------------- phase-1 role ----------------
        int blk = blockIdx.x;
        int b = blk >> 3;
        const float* hm = hm_all + (size_t)b * HM_W * HM_H;
        int rbase = ((blk & 7) * 4 + wave) * 16;   // max 496 < PW: all waves active

        float w0[8], w1[8], w2[8], w3[8], w4[8];
        load_row8(hm, rbase + 0, c0, w0);
        load_row8(hm, rbase + 1, c0, w1);
        load_row8(hm, rbase + 2, c0, w2);
        load_row8(hm, rbase + 3, c0, w3);

#pragma unroll
        for (int rr = 0; rr < 16; ++rr) {
            int y = rbase + rr;
            if (y >= PW) break;                 // wave-uniform
            load_row8(hm, y + 4, c0, w4);
            float s[8];
#pragma unroll
            for (int j = 0; j < 8; ++j)
                s[j] = ((((w0[j] + w1[j]) + w2[j]) + w3[j]) + w4[j]);
            float bv; int bc;
            row_best_shfl(s, lane, bv, bc);
            if (lane == 0) {
                rowv_ws[b * 512 + y] = bv;
                rowc_ws[b * 512 + y] = bc;
            }
#pragma unroll
            for (int j = 0; j < 8; ++j) { w0[j] = w1[j]; w1[j] = w2[j]; w2[j] = w3[j]; w3[j] = w4[j]; }
        }

        __syncthreads();   // all waves' ws stores drained (compiler: vmcnt(0) before barrier)
        if (t == 0)        // RELEASE: writeback XCD L2 so readers on other XCDs see the rows
            __hip_atomic_fetch_add(&cnt[b], 1, __ATOMIC_RELEASE, __HIP_MEMORY_SCOPE_AGENT);
        return;
    }

    // ---------------- phase-2 role ----------------
    int b = blockIdx.x - 1024;
    const float* hm = hm_all + (size_t)b * HM_W * HM_H;

    if (t == 0) {
        while (__hip_atomic_load(&cnt[b], __ATOMIC_ACQUIRE, __HIP_MEMORY_SCOPE_AGENT) < 8)
            __builtin_amdgcn_s_sleep(2);
    }
    __syncthreads();       // all threads ordered after t0's acquire (L2 invalidated)

    for (int i = t; i < 512; i += 256) {
        if (i < PW) { rowv[i] = rowv_ws[b * 512 + i]; rowc[i] = rowc_ws[b * 512 + i]; }
        else        { rowv[i] = -__builtin_inff();    rowc[i] = 0; }
    }
    if (t == 0) { upd_y0[1] = -1000; upd_n[1] = 0; }   // it=0 reads pbuf=1: empty

    int zrr[6], zcc[6];

#pragma unroll
    for (int it = 0; it < 6; ++it) {
        __syncthreads();   // the ONLY barrier per iteration

        int pbuf = (it + 1) & 1;           // buffer written by previous iteration
        int py0 = upd_y0[pbuf];            // block-uniform
        int pn  = upd_n[pbuf];

        // ---- per-thread argmax over 8 stride-64 entries, overriding stale rows ----
        float bv = -__builtin_inff(); int bi = 0x7fffffff;
#pragma unroll
        for (int j = 0; j < 8; ++j) {
            int idx = j * 64 + lane;
            float v = rowv[idx];
            unsigned u = (unsigned)(idx - py0);
            if (u < (unsigned)pn) v = updv[pbuf][u];
            if (v > bv) { bv = v; bi = idx; }   // ascending idx keeps lowest row on tie
        }
#pragma unroll
        for (int m = 1; m < 64; m <<= 1) {
            float ov = __shfl_xor(bv, m);
            int   oi = __shfl_xor(bi, m);
            if (ov > bv || (ov == bv && oi < bi)) { bv = ov; bi = oi; }
        }
        int fr = bi;
        unsigned uf = (unsigned)(fr - py0);
        int fc = (uf < (unsigned)pn) ? updc[pbuf][uf] : rowc[fr];   // LDS broadcast
        zrr[it] = fr; zcc[it] = fc;
        if (t == 0) {
            out[b * 12 + it * 2 + 0] = fc + 2;   // SWAP_RC: (c+R, r+R)
            out[b * 12 + it * 2 + 1] = fr + 2;
        }

        // ---- patch rowv/rowc with the previous iteration's repairs ----
        // Concurrent with the reads above, race-benign: any racy read is
        // discarded via the override, and patch writes carry identical values.
        if (t < 9 && t < pn) {
            int yy = py0 + t;
            rowv[yy] = updv[pbuf][t];
            rowc[yy] = updc[pbuf][t];
        }

        if (it == 5) break;                // compile-time: last peak needs no repair

        // ---- repair the <=9 affected rows: wave w does rows y0+w+4p, p<3 ----
        int y0 = fr - 4 < 0 ? 0 : fr - 4;
        int y1 = fr + 4 > PW - 1 ? PW - 1 : fr + 4;
        int buf = it & 1;
#pragma unroll
        for (int p = 0; p < 3; ++p) {
            int li = wave + p * 4;         // wave-uniform
            int y = y0 + li;
            if (li < 9 && y <= y1) {
                float s[8];
#pragma unroll
                for (int j = 0; j < 8; ++j) s[j] = 0.f;
#pragma unroll
                for (int i = 0; i < 5; ++i) {
                    float v[8];
                    load_row8(hm, y + i, c0, v);
#pragma unroll
                    for (int j = 0; j < 8; ++j) {
                        float vv = v[j];
#pragma unroll
                        for (int k = 0; k < 6; ++k) {
                            if (k <= it && (unsigned)(y + i - zrr[k]) < 5u
                                        && (unsigned)(c0 + j - zcc[k]) < 5u)
                                vv = 0.f;
                        }
                        s[j] += vv;
                    }
                }
                float nv; int nc;
                row_best_shfl(s, lane, nv, nc);
                if (lane == 0) { updv[buf][li] = nv; updc[buf][li] = nc; }
            }
        }
        if (t == 0) { upd_y0[buf] = y0; upd_n[buf] = y1 - y0 + 1; }
    }
}

extern "C" void kernel_launch(void* const* d_in, const int* in_sizes, int n_in,
                              void* d_out, int out_size, void* d_ws, size_t ws_size,
                              hipStream_t stream) {
    const float* hm = (const float*)d_in[0];
    int* out = (int*)d_out;
    float* rowv_ws = (float*)d_ws;
    int*   rowc_ws = (int*)((char*)d_ws + (size_t)128 * 512 * sizeof(float));
    int*   cnt     = (int*)((char*)d_ws + (size_t)2 * 128 * 512 * sizeof(float));

    hipMemsetAsync(cnt, 0, NBATCH * sizeof(int), stream);
    fused_kernel<<<dim3(1024 + NBATCH), dim3(256), 0, stream>>>(hm, rowv_ws, rowc_ws, cnt, out);
}

// Round 10
// 58.668 us; speedup vs baseline: 1.7704x; 1.7704x over previous
//
#include <hip/hip_runtime.h>
#include <hip/hip_bf16.h>

#define HM_W 512
#define HM_H 512
#define PW   508   // 512 - 5 + 1

__device__ __forceinline__ void load_row8(const float* __restrict__ hm, int y, int c0, float v[8]) {
    const float4* rp = reinterpret_cast<const float4*>(hm + y * HM_W + c0);
    float4 a = rp[0];
    float4 b = rp[1];
    v[0]=a.x; v[1]=a.y; v[2]=a.z; v[3]=a.w;
    v[4]=b.x; v[5]=b.y; v[6]=b.z; v[7]=b.w;
}

// Per-lane 5-wide window sums from per-lane colsums s[0..7] (cols lane*8..lane*8+7),
// cross-lane tail via shfl, then wave-wide argmax (tie-break: lowest column).
// Whole wave must be active. All lanes end with the result.
__device__ __forceinline__ void row_best_shfl(const float s[8], int lane, float& bv, int& bc) {
    float cb[12];
#pragma unroll
    for (int j = 0; j < 8; ++j) cb[j] = s[j];
#pragma unroll
    for (int j = 0; j < 4; ++j) cb[8 + j] = __shfl_down(s[j], 1);
    bv = -__builtin_inff();
    bc = 0x7fffffff;
    int c0 = lane * 8;
#pragma unroll
    for (int j = 0; j < 8; ++j) {
        int c = c0 + j;
        float w = cb[j] + cb[j + 1] + cb[j + 2] + cb[j + 3] + cb[j + 4];
        if (c < PW && w > bv) { bv = w; bc = c; }   // ascending c keeps lowest col on tie
    }
#pragma unroll
    for (int m = 1; m < 64; m <<= 1) {
        float ov = __shfl_xor(bv, m);
        int   oc = __shfl_xor(bc, m);
        if (ov > bv || (ov == bv && oc < bc)) { bv = ov; bc = oc; }
    }
}

// Phase 1: rolling 5-row register window, 8 output rows per wave.
// L3 holds the whole input during timing (round-9 evidence: warm-replay
// FETCH_SIZE ~= 1.5 MB), so the 1.5x read redundancy is L2/L3-absorbed;
// the binding constraint is latency overlap. grid = (16,128) = 2048 blocks
// = 8 blocks/CU = 8 waves/SIMD (VGPR ~56 allows 32 waves/CU), block = 256.
__global__ void phase1_kernel(const float* __restrict__ hm_all,
                              float* __restrict__ rowv_ws, int* __restrict__ rowc_ws) {
    int b = blockIdx.y;
    int wave = threadIdx.x >> 6;
    int lane = threadIdx.x & 63;
    int c0 = lane * 8;
    const float* hm = hm_all + (size_t)b * HM_W * HM_H;

    int rbase = (blockIdx.x * 4 + wave) * 8;   // max 504 < PW: every wave has work

    float w0[8], w1[8], w2[8], w3[8], w4[8];
    load_row8(hm, rbase + 0, c0, w0);
    load_row8(hm, rbase + 1, c0, w1);
    load_row8(hm, rbase + 2, c0, w2);
    load_row8(hm, rbase + 3, c0, w3);

#pragma unroll
    for (int rr = 0; rr < 8; ++rr) {
        int y = rbase + rr;
        if (y >= PW) break;                 // wave-uniform
        load_row8(hm, y + 4, c0, w4);       // y+4 <= 511: in bounds
        float s[8];
#pragma unroll
        for (int j = 0; j < 8; ++j)
            s[j] = ((((w0[j] + w1[j]) + w2[j]) + w3[j]) + w4[j]);
        float bv; int bc;
        row_best_shfl(s, lane, bv, bc);
        if (lane == 0) {
            rowv_ws[b * 512 + y] = bv;
            rowc_ws[b * 512 + y] = bc;
        }
#pragma unroll
        for (int j = 0; j < 8; ++j) { w0[j] = w1[j]; w1[j] = w2[j]; w2[j] = w3[j]; w3[j] = w4[j]; }
    }
}

// Phase 2 (round-6 exact, best known): LDS row table + ONE barrier per iteration.
// Repairs write a tiny double-buffered side buffer; next iteration's argmax
// overrides stale rowv entries from it while 9 threads patch rowv in place
// (race-benign: readers discard any racy read via the override; writes carry the
// identical value). grid = 128, block = 640 (10 waves; waves 0..8 repair rows).
__global__ void __launch_bounds__(640) phase2_kernel(const float* __restrict__ hm_all,
                              const float* __restrict__ rowv_ws,
                              const int* __restrict__ rowc_ws,
                              int* __restrict__ out) {
    int b = blockIdx.x;
    const float* hm = hm_all + (size_t)b * HM_W * HM_H;
    int t = threadIdx.x;
    int wave = t >> 6, lane = t & 63;
    int c0 = lane * 8;

    __shared__ float rowv[512];
    __shared__ int   rowc[512];
    __shared__ float updv[2][9];
    __shared__ int   updc[2][9];
    __shared__ int   upd_y0[2];
    __shared__ int   upd_n[2];

    if (t < 512) {
        if (t < PW) { rowv[t] = rowv_ws[b * 512 + t]; rowc[t] = rowc_ws[b * 512 + t]; }
        else        { rowv[t] = -__builtin_inff();    rowc[t] = 0; }
    }
    if (t == 0) { upd_y0[1] = -1000; upd_n[1] = 0; }   // it=0 reads pbuf=1: empty

    int zrr[6], zcc[6];

#pragma unroll
    for (int it = 0; it < 6; ++it) {
        __syncthreads();   // the ONLY barrier: prev repair writes -> this iter's reads

        int pbuf = (it + 1) & 1;           // buffer written by previous iteration
        int py0 = upd_y0[pbuf];            // block-uniform
        int pn  = upd_n[pbuf];

        // ---- per-thread argmax over 8 stride-64 entries, overriding stale rows ----
        float bv = -__builtin_inff(); int bi = 0x7fffffff;
#pragma unroll
        for (int j = 0; j < 8; ++j) {
            int idx = j * 64 + lane;
            float v = rowv[idx];
            unsigned u = (unsigned)(idx - py0);
            if (u < (unsigned)pn) v = updv[pbuf][u];
            if (v > bv) { bv = v; bi = idx; }   // ascending idx keeps lowest row on tie
        }
#pragma unroll
        for (int m = 1; m < 64; m <<= 1) {
            float ov = __shfl_xor(bv, m);
            int   oi = __shfl_xor(bi, m);
            if (ov > bv || (ov == bv && oi < bi)) { bv = ov; bi = oi; }
        }
        int fr = bi;
        unsigned uf = (unsigned)(fr - py0);
        int fc = (uf < (unsigned)pn) ? updc[pbuf][uf] : rowc[fr];   // LDS broadcast
        zrr[it] = fr; zcc[it] = fc;
        if (t == 0) {
            out[b * 12 + it * 2 + 0] = fc + 2;   // SWAP_RC: (c+R, r+R)
            out[b * 12 + it * 2 + 1] = fr + 2;
        }

        // ---- patch rowv/rowc with the previous iteration's repairs ----
        // Concurrent with the reads above, but race-benign (see header comment).
        if (t < 9 && t < pn) {
            int yy = py0 + t;
            rowv[yy] = updv[pbuf][t];
            rowc[yy] = updc[pbuf][t];
        }

        if (it == 5) break;                // compile-time: last peak needs no repair

        // ---- repair the <=9 affected rows, one wave each; loads issue now ----
        int y0 = fr - 4 < 0 ? 0 : fr - 4;
        int y1 = fr + 4 > PW - 1 ? PW - 1 : fr + 4;
        int buf = it & 1;
        int y = y0 + wave;                 // wave-uniform predicate
        if (wave < 9 && y <= y1) {
            float s[8];
#pragma unroll
            for (int j = 0; j < 8; ++j) s[j] = 0.f;
#pragma unroll
            for (int i = 0; i < 5; ++i) {
                float v[8];
                load_row8(hm, y + i, c0, v);
#pragma unroll
                for (int j = 0; j < 8; ++j) {
                    float vv = v[j];
#pragma unroll
                    for (int k = 0; k < 6; ++k) {
                        if (k <= it && (unsigned)(y + i - zrr[k]) < 5u
                                    && (unsigned)(c0 + j - zcc[k]) < 5u)
                            vv = 0.f;
                    }
                    s[j] += vv;
                }
            }
            float nv; int nc;
            row_best_shfl(s, lane, nv, nc);
            if (lane == 0) { updv[buf][wave] = nv; updc[buf][wave] = nc; }
        }
        if (t == 0) { upd_y0[buf] = y0; upd_n[buf] = y1 - y0 + 1; }
    }
}

extern "C" void kernel_launch(void* const* d_in, const int* in_sizes, int n_in,
                              void* d_out, int out_size, void* d_ws, size_t ws_size,
                              hipStream_t stream) {
    const float* hm = (const float*)d_in[0];
    int* out = (int*)d_out;
    float* rowv_ws = (float*)d_ws;
    int*   rowc_ws = (int*)((char*)d_ws + (size_t)128 * 512 * sizeof(float));

    phase1_kernel<<<dim3(16, 128), dim3(256), 0, stream>>>(hm, rowv_ws, rowc_ws);
    phase2_kernel<<<dim3(128), dim3(640), 0, stream>>>(hm, rowv_ws, rowc_ws, out);
}